// Round 10
// baseline (211.350 us; speedup 1.0000x reference)
//
#include <hip/hip_runtime.h>
#include <stdint.h>

#define N_NODES 100000
#define N_EDGES 600000
#define CAP 64   // per-node bucket capacity (proven in R8); max in-degree ~22 here
// D_IN = D_H = 128, D_OUT = 2. All float tensors fp32; edge_index int32.
// h1 stored bf16; GEMM1 on MFMA bf16. Fixed-capacity buckets (no scan).
// R7 lesson: grid.sync() ~60us/barrier on MI355X — never fuse via cooperative launch.
// R9 lesson: split-half divergent-shfl agg loop failed on HW; keep R8's uniform form.

typedef __attribute__((ext_vector_type(8))) short bf16x8;
typedef __attribute__((ext_vector_type(4))) float f32x4;

__device__ __forceinline__ float bflo(unsigned int u) { return __uint_as_float(u << 16); }
__device__ __forceinline__ float bfhi(unsigned int u) { return __uint_as_float(u & 0xffff0000u); }
__device__ __forceinline__ unsigned int f2bf(float f) {  // RNE, returns low 16
    unsigned int u = __float_as_uint(f);
    return (u + 0x7fffu + ((u >> 16) & 1u)) >> 16;
}

// Fused GEMM1 + edge bucket-scatter (single launch; block-range split).
// Blocks [0,1563): h1b = bf16(x @ W1) via MFMA bf16, 64 rows/block.
//   W1 transposed+cast to LDS in-block (no precomputed W1T -> no ordering hazard).
// Blocks [1563,3907): edge scatter edata[col*CAP + pos] = row, pos via atomic cnt.
__global__ __launch_bounds__(256) void k_fused(const float* __restrict__ x,
                                               const float* __restrict__ W1,
                                               const int* __restrict__ ei,
                                               int* __restrict__ cnt,
                                               int* __restrict__ edata,
                                               unsigned short* __restrict__ h1b) {
    __shared__ unsigned short sxb[64][136];   // x tile, bf16; reused for D staging
    __shared__ unsigned short sw[128][136];   // W1^T, bf16: sw[n][k]
    const int tid = threadIdx.x;
    const int b = blockIdx.x;
    if (b >= 1563) {                          // ---- bucket part ----
        int e = (b - 1563) * 256 + tid;
        if (e < N_EDGES) {
            int r = ei[e];
            int c = ei[N_EDGES + e];
            int pos = atomicAdd(&cnt[c], 1);
            if (pos < CAP) edata[(size_t)c * CAP + pos] = r;
        }
        return;
    }
    // ---- GEMM part ----
    const int rowBase = b * 64;
#pragma unroll
    for (int i = 0; i < 8; i++) {            // stage x: 2048 float4 -> bf16
        int flat = tid + 256 * i;
        int row = flat >> 5;
        int f4 = flat & 31;
        int grow = rowBase + row;
        if (grow > N_NODES - 1) grow = N_NODES - 1;
        float4 v = *(const float4*)(x + (size_t)grow * 128 + f4 * 4);
        ushort4 p;
        p.x = (unsigned short)f2bf(v.x);
        p.y = (unsigned short)f2bf(v.y);
        p.z = (unsigned short)f2bf(v.z);
        p.w = (unsigned short)f2bf(v.w);
        *(ushort4*)(&sxb[row][f4 * 4]) = p;
    }
    // stage W1 transposed: flat float4 id f in [0,4096): k = f&127, n4 = (f>>7)*4.
    // Global: lane-strided rows (W1 64KB, L1/L2-resident). LDS write banks:
    // (4*(n4+j) + k/2) mod 32 with k consecutive across lanes -> 32 banks 2-way (free).
#pragma unroll
    for (int i = 0; i < 16; i++) {
        int flat = tid + 256 * i;
        int k = flat & 127;
        int n4 = (flat >> 7) * 4;
        float4 v = *(const float4*)(W1 + (size_t)k * 128 + n4);
        sw[n4 + 0][k] = (unsigned short)f2bf(v.x);
        sw[n4 + 1][k] = (unsigned short)f2bf(v.y);
        sw[n4 + 2][k] = (unsigned short)f2bf(v.z);
        sw[n4 + 3][k] = (unsigned short)f2bf(v.w);
    }
    __syncthreads();

    const int wv = tid >> 6;
    const int lane = tid & 63;
    const int l16 = lane & 15;
    const int quad = lane >> 4;
    f32x4 acc[8];
#pragma unroll
    for (int t = 0; t < 8; t++) acc[t] = (f32x4){0.f, 0.f, 0.f, 0.f};

#pragma unroll
    for (int k0 = 0; k0 < 128; k0 += 32) {
        bf16x8 a = *(const bf16x8*)(&sxb[wv * 16 + l16][k0 + quad * 8]);
#pragma unroll
        for (int t = 0; t < 8; t++) {
            bf16x8 bfr = *(const bf16x8*)(&sw[t * 16 + l16][k0 + quad * 8]);
            acc[t] = __builtin_amdgcn_mfma_f32_16x16x32_bf16(a, bfr, acc[t], 0, 0, 0);
        }
    }
    __syncthreads();                          // LDS reads done; reuse sxb for D
#pragma unroll
    for (int t = 0; t < 8; t++)
#pragma unroll
        for (int r = 0; r < 4; r++)
            sxb[wv * 16 + quad * 4 + r][t * 16 + l16] = (unsigned short)f2bf(acc[t][r]);
    __syncthreads();
#pragma unroll
    for (int i = 0; i < 4; i++) {             // coalesced store: 1024 uint4
        int flat = tid + 256 * i;
        int row = flat >> 4;
        int c8 = flat & 15;
        int grow = rowBase + row;
        if (grow < N_NODES)
            *(uint4*)(h1b + (size_t)grow * 128 + c8 * 8) = *(const uint4*)(&sxb[row][c8 * 8]);
    }
}

// Layer-1 aggregation (bf16 gather over buckets) + bias1+ReLU+GEMM2 epilogue.
// One wave per node; lane l owns cols 2l,2l+1. Norms from cnt on the fly.
// (R8-proven form: uniform preload, wave-uniform loop.)
__global__ __launch_bounds__(256) void k_agg1(const unsigned short* __restrict__ h1b,
                                              const int* __restrict__ edata,
                                              const int* __restrict__ cnt,
                                              const float* __restrict__ b1,
                                              const float* __restrict__ W2,
                                              float* __restrict__ h2) {
    int g = blockIdx.x * 256 + threadIdx.x;
    int node = g >> 6;   // exact grid: 25000 blocks * 4 waves
    int lane = g & 63;
    int c = cnt[node];                      // wave-uniform (same address)
    int cc = (c < CAP) ? c : CAP;
    float d = rsqrtf((float)c + 1.0f);
    float d2 = d * d;
    unsigned int us = *(const unsigned int*)(h1b + (size_t)node * 128 + lane * 2);
    float ax = bflo(us) * d2, ay = bfhi(us) * d2;

    int src_l = 0; float nrm_l = 0.0f;
    if (cc > 0) {
        src_l = edata[(size_t)node * CAP + (lane < cc ? lane : cc - 1)];
        nrm_l = rsqrtf((float)cnt[src_l] + 1.0f) * d;
    }
    int i = 0;
    for (; i + 4 <= cc; i += 4) {
        int s0 = __shfl(src_l, i), s1 = __shfl(src_l, i + 1);
        int s2 = __shfl(src_l, i + 2), s3 = __shfl(src_l, i + 3);
        float n0 = __shfl(nrm_l, i), n1 = __shfl(nrm_l, i + 1);
        float n2 = __shfl(nrm_l, i + 2), n3 = __shfl(nrm_l, i + 3);
        unsigned int u0 = *(const unsigned int*)(h1b + (size_t)s0 * 128 + lane * 2);
        unsigned int u1 = *(const unsigned int*)(h1b + (size_t)s1 * 128 + lane * 2);
        unsigned int u2 = *(const unsigned int*)(h1b + (size_t)s2 * 128 + lane * 2);
        unsigned int u3 = *(const unsigned int*)(h1b + (size_t)s3 * 128 + lane * 2);
        ax = fmaf(bflo(u0), n0, ax); ay = fmaf(bfhi(u0), n0, ay);
        ax = fmaf(bflo(u1), n1, ax); ay = fmaf(bfhi(u1), n1, ay);
        ax = fmaf(bflo(u2), n2, ax); ay = fmaf(bfhi(u2), n2, ay);
        ax = fmaf(bflo(u3), n3, ax); ay = fmaf(bfhi(u3), n3, ay);
    }
    for (; i < cc; i++) {
        int s = __shfl(src_l, i);
        float n = __shfl(nrm_l, i);
        unsigned int u = *(const unsigned int*)(h1b + (size_t)s * 128 + lane * 2);
        ax = fmaf(bflo(u), n, ax); ay = fmaf(bfhi(u), n, ay);
    }

    float2 bb = *(const float2*)(b1 + lane * 2);
    float v0 = fmaxf(ax + bb.x, 0.0f);
    float v1 = fmaxf(ay + bb.y, 0.0f);
    float4 w = *(const float4*)(W2 + lane * 4);
    float p0 = v0 * w.x + v1 * w.z;
    float p1 = v0 * w.y + v1 * w.w;
    for (int offl = 32; offl; offl >>= 1) {
        p0 += __shfl_xor(p0, offl);
        p1 += __shfl_xor(p1, offl);
    }
    if (lane == 0) *(float2*)(h2 + (size_t)node * 2) = make_float2(p0, p1);
}

// Layer-2 aggregation: thread per node; h2 (800 KB) and cnt L2-resident.
__global__ void k_agg2(const float* __restrict__ h2, const int* __restrict__ edata,
                       const int* __restrict__ cnt, const float* __restrict__ b2,
                       float* __restrict__ out) {
    int n = blockIdx.x * 256 + threadIdx.x;
    if (n >= N_NODES) return;
    int c = cnt[n];
    int cc = (c < CAP) ? c : CAP;
    float d = rsqrtf((float)c + 1.0f);
    float d2 = d * d;
    float2 h = *(const float2*)(h2 + (size_t)n * 2);
    float o0 = h.x * d2, o1 = h.y * d2;
    for (int i = 0; i < cc; i++) {
        int src = edata[(size_t)n * CAP + i];
        float nrm = rsqrtf((float)cnt[src] + 1.0f) * d;
        float2 v = *(const float2*)(h2 + (size_t)src * 2);
        o0 = fmaf(v.x, nrm, o0);
        o1 = fmaf(v.y, nrm, o1);
    }
    *(float2*)(out + (size_t)n * 2) = make_float2(o0 + b2[0], o1 + b2[1]);
}

extern "C" void kernel_launch(void* const* d_in, const int* in_sizes, int n_in,
                              void* d_out, int out_size, void* d_ws, size_t ws_size,
                              hipStream_t stream) {
    const float* x  = (const float*)d_in[0];   // [N,128]
    const int* ei   = (const int*)d_in[1];     // [2,E] int32
    const float* W1 = (const float*)d_in[2];   // [128,128]
    const float* b1 = (const float*)d_in[3];   // [128]
    const float* W2 = (const float*)d_in[4];   // [128,2]
    const float* b2 = (const float*)d_in[5];   // [2]
    float* out = (float*)d_out;                // [N,2]

    char* w = (char*)d_ws;
    int*   cnt   = (int*)w;                     w += 100096 * 4;
    int*   edata = (int*)w;                     w += (size_t)N_NODES * CAP * 4;  // 25.6 MB
    unsigned short* h1b = (unsigned short*)w;   w += (size_t)N_NODES * 128 * 2;  // 25.6 MB
    float* h2    = (float*)w;                   // N*2 floats

    hipMemsetAsync(cnt, 0, 100096 * 4, stream);
    k_fused<<<3907, 256, 0, stream>>>(x, W1, ei, cnt, edata, h1b);
    k_agg1 <<<25000, 256, 0, stream>>>(h1b, edata, cnt, b1, W2, h2);
    k_agg2 <<<391, 256, 0, stream>>>(h2, edata, cnt, b2, out);
}

// Round 11
// 199.976 us; speedup vs baseline: 1.0569x; 1.0569x over previous
//
#include <hip/hip_runtime.h>
#include <stdint.h>

#define N_NODES 100000
#define N_EDGES 600000
#define CAP 64   // per-node bucket capacity (proven R8); max in-degree ~22 here
// D_IN = D_H = 128, D_OUT = 2. All float tensors fp32; edge_index int32.
// h1 stored bf16; GEMM1 on MFMA bf16. Fixed-capacity buckets (no scan).
// R7 lesson: grid.sync() ~60us/barrier on MI355X — never fuse via cooperative launch.
// R9 lesson: split-half divergent-shfl agg loop failed on HW; keep R8's uniform form.
// R10 lesson: LDS is reserved for EVERY block of a kernel — mixed-block fusion
// requires compatible footprints. Fixed here by pre-baking W1 into B-frag order
// (32 KB global, coalesced) so the fused kernel only needs the 17 KB x-tile.

typedef __attribute__((ext_vector_type(8))) short bf16x8;
typedef __attribute__((ext_vector_type(4))) float f32x4;

__device__ __forceinline__ float bflo(unsigned int u) { return __uint_as_float(u << 16); }
__device__ __forceinline__ float bfhi(unsigned int u) { return __uint_as_float(u & 0xffff0000u); }
__device__ __forceinline__ unsigned int f2bf(float f) {  // RNE, returns low 16
    unsigned int u = __float_as_uint(f);
    return (u + 0x7fffu + ((u >> 16) & 1u)) >> 16;
}

// Pre-pass: zero cnt (blocks [0,391)) + bake W1 into MFMA B-fragment order
// (blocks [391,455)). W1f[((t*4+k0c)*64+lane)*8+j] = bf16(W1[k][n]) with
// n = t*16+(lane&15), k = k0c*32+(lane>>4)*8+j  — exactly the bf16x8 lane frag.
__global__ void k_pre(const float* __restrict__ W1, int* __restrict__ cnt,
                      unsigned short* __restrict__ W1f) {
    int b = blockIdx.x;
    if (b < 391) {
        int gid = b * 256 + threadIdx.x;   // 391*256 = 100096 exact
        cnt[gid] = 0;
        return;
    }
    int idx = (b - 391) * 256 + threadIdx.x;  // 0..16383
    int t = idx >> 11;
    int k0c = (idx >> 9) & 3;
    int lane = (idx >> 3) & 63;
    int j = idx & 7;
    int n = t * 16 + (lane & 15);
    int k = k0c * 32 + (lane >> 4) * 8 + j;
    W1f[idx] = (unsigned short)f2bf(W1[k * 128 + n]);
}

// Fused edge bucket-scatter + GEMM1 (single launch; block-range split).
// Blocks [0,2344): scatter edata[col*CAP+pos]=row, pos via atomic cnt.
// Blocks [2344,3907): h1b = bf16(x @ W1) via MFMA, 64 rows/block, B-frags
// loaded coalesced from W1f (L1/L2-hot). LDS = 17.4 KB -> 8 blocks/CU, so
// scatter blocks keep ~full wave occupancy (the R10 failure mode).
__global__ __launch_bounds__(256) void k_fused(const float* __restrict__ x,
                                               const unsigned short* __restrict__ W1f,
                                               const int* __restrict__ ei,
                                               int* __restrict__ cnt,
                                               int* __restrict__ edata,
                                               unsigned short* __restrict__ h1b) {
    __shared__ unsigned short sxb[64][136];   // x tile bf16; reused for D staging
    const int tid = threadIdx.x;
    const int b = blockIdx.x;
    if (b < 2344) {                           // ---- scatter part ----
        int e = b * 256 + tid;
        if (e < N_EDGES) {
            int r = ei[e];
            int c = ei[N_EDGES + e];
            int pos = atomicAdd(&cnt[c], 1);
            if (pos < CAP) edata[(size_t)c * CAP + pos] = r;
        }
        return;
    }
    // ---- GEMM part ----
    const int rowBase = (b - 2344) * 64;
#pragma unroll
    for (int i = 0; i < 8; i++) {            // stage x: 2048 float4 -> bf16
        int flat = tid + 256 * i;
        int row = flat >> 5;
        int f4 = flat & 31;
        int grow = rowBase + row;
        if (grow > N_NODES - 1) grow = N_NODES - 1;
        float4 v = *(const float4*)(x + (size_t)grow * 128 + f4 * 4);
        ushort4 p;
        p.x = (unsigned short)f2bf(v.x);
        p.y = (unsigned short)f2bf(v.y);
        p.z = (unsigned short)f2bf(v.z);
        p.w = (unsigned short)f2bf(v.w);
        *(ushort4*)(&sxb[row][f4 * 4]) = p;
    }
    __syncthreads();

    const int wv = tid >> 6;
    const int lane = tid & 63;
    const int l16 = lane & 15;
    const int quad = lane >> 4;
    const bf16x8* __restrict__ wf = (const bf16x8*)W1f;
    f32x4 acc[8];
#pragma unroll
    for (int t = 0; t < 8; t++) acc[t] = (f32x4){0.f, 0.f, 0.f, 0.f};

#pragma unroll
    for (int k0c = 0; k0c < 4; k0c++) {
        bf16x8 a = *(const bf16x8*)(&sxb[wv * 16 + l16][k0c * 32 + quad * 8]);
#pragma unroll
        for (int t = 0; t < 8; t++) {
            bf16x8 bfr = wf[(t * 4 + k0c) * 64 + lane];   // coalesced, L1-hot
            acc[t] = __builtin_amdgcn_mfma_f32_16x16x32_bf16(a, bfr, acc[t], 0, 0, 0);
        }
    }
    __syncthreads();                          // LDS reads done; reuse sxb for D
#pragma unroll
    for (int t = 0; t < 8; t++)
#pragma unroll
        for (int r = 0; r < 4; r++)
            sxb[wv * 16 + quad * 4 + r][t * 16 + l16] = (unsigned short)f2bf(acc[t][r]);
    __syncthreads();
#pragma unroll
    for (int i = 0; i < 4; i++) {             // coalesced store: 1024 uint4
        int flat = tid + 256 * i;
        int row = flat >> 4;
        int c8 = flat & 15;
        int grow = rowBase + row;
        if (grow < N_NODES)
            *(uint4*)(h1b + (size_t)grow * 128 + c8 * 8) = *(const uint4*)(&sxb[row][c8 * 8]);
    }
}

// Layer-1 aggregation (bf16 gather over buckets) + bias1+ReLU+GEMM2 epilogue.
// One wave per node; lane l owns cols 2l,2l+1. (R8-proven form.)
__global__ __launch_bounds__(256) void k_agg1(const unsigned short* __restrict__ h1b,
                                              const int* __restrict__ edata,
                                              const int* __restrict__ cnt,
                                              const float* __restrict__ b1,
                                              const float* __restrict__ W2,
                                              float* __restrict__ h2) {
    int g = blockIdx.x * 256 + threadIdx.x;
    int node = g >> 6;   // exact grid: 25000 blocks * 4 waves
    int lane = g & 63;
    int c = cnt[node];                      // wave-uniform (same address)
    int cc = (c < CAP) ? c : CAP;
    float d = rsqrtf((float)c + 1.0f);
    float d2 = d * d;
    unsigned int us = *(const unsigned int*)(h1b + (size_t)node * 128 + lane * 2);
    float ax = bflo(us) * d2, ay = bfhi(us) * d2;

    int src_l = 0; float nrm_l = 0.0f;
    if (cc > 0) {
        src_l = edata[(size_t)node * CAP + (lane < cc ? lane : cc - 1)];
        nrm_l = rsqrtf((float)cnt[src_l] + 1.0f) * d;
    }
    int i = 0;
    for (; i + 4 <= cc; i += 4) {
        int s0 = __shfl(src_l, i), s1 = __shfl(src_l, i + 1);
        int s2 = __shfl(src_l, i + 2), s3 = __shfl(src_l, i + 3);
        float n0 = __shfl(nrm_l, i), n1 = __shfl(nrm_l, i + 1);
        float n2 = __shfl(nrm_l, i + 2), n3 = __shfl(nrm_l, i + 3);
        unsigned int u0 = *(const unsigned int*)(h1b + (size_t)s0 * 128 + lane * 2);
        unsigned int u1 = *(const unsigned int*)(h1b + (size_t)s1 * 128 + lane * 2);
        unsigned int u2 = *(const unsigned int*)(h1b + (size_t)s2 * 128 + lane * 2);
        unsigned int u3 = *(const unsigned int*)(h1b + (size_t)s3 * 128 + lane * 2);
        ax = fmaf(bflo(u0), n0, ax); ay = fmaf(bfhi(u0), n0, ay);
        ax = fmaf(bflo(u1), n1, ax); ay = fmaf(bfhi(u1), n1, ay);
        ax = fmaf(bflo(u2), n2, ax); ay = fmaf(bfhi(u2), n2, ay);
        ax = fmaf(bflo(u3), n3, ax); ay = fmaf(bfhi(u3), n3, ay);
    }
    for (; i < cc; i++) {
        int s = __shfl(src_l, i);
        float n = __shfl(nrm_l, i);
        unsigned int u = *(const unsigned int*)(h1b + (size_t)s * 128 + lane * 2);
        ax = fmaf(bflo(u), n, ax); ay = fmaf(bfhi(u), n, ay);
    }

    float2 bb = *(const float2*)(b1 + lane * 2);
    float v0 = fmaxf(ax + bb.x, 0.0f);
    float v1 = fmaxf(ay + bb.y, 0.0f);
    float4 w = *(const float4*)(W2 + lane * 4);
    float p0 = v0 * w.x + v1 * w.z;
    float p1 = v0 * w.y + v1 * w.w;
    for (int offl = 32; offl; offl >>= 1) {
        p0 += __shfl_xor(p0, offl);
        p1 += __shfl_xor(p1, offl);
    }
    if (lane == 0) *(float2*)(h2 + (size_t)node * 2) = make_float2(p0, p1);
}

// Layer-2 aggregation: thread per node; h2 (800 KB) and cnt L2-resident.
__global__ void k_agg2(const float* __restrict__ h2, const int* __restrict__ edata,
                       const int* __restrict__ cnt, const float* __restrict__ b2,
                       float* __restrict__ out) {
    int n = blockIdx.x * 256 + threadIdx.x;
    if (n >= N_NODES) return;
    int c = cnt[n];
    int cc = (c < CAP) ? c : CAP;
    float d = rsqrtf((float)c + 1.0f);
    float d2 = d * d;
    float2 h = *(const float2*)(h2 + (size_t)n * 2);
    float o0 = h.x * d2, o1 = h.y * d2;
    for (int i = 0; i < cc; i++) {
        int src = edata[(size_t)n * CAP + i];
        float nrm = rsqrtf((float)cnt[src] + 1.0f) * d;
        float2 v = *(const float2*)(h2 + (size_t)src * 2);
        o0 = fmaf(v.x, nrm, o0);
        o1 = fmaf(v.y, nrm, o1);
    }
    *(float2*)(out + (size_t)n * 2) = make_float2(o0 + b2[0], o1 + b2[1]);
}

extern "C" void kernel_launch(void* const* d_in, const int* in_sizes, int n_in,
                              void* d_out, int out_size, void* d_ws, size_t ws_size,
                              hipStream_t stream) {
    const float* x  = (const float*)d_in[0];   // [N,128]
    const int* ei   = (const int*)d_in[1];     // [2,E] int32
    const float* W1 = (const float*)d_in[2];   // [128,128]
    const float* b1 = (const float*)d_in[3];   // [128]
    const float* W2 = (const float*)d_in[4];   // [128,2]
    const float* b2 = (const float*)d_in[5];   // [2]
    float* out = (float*)d_out;                // [N,2]

    char* w = (char*)d_ws;
    int*   cnt   = (int*)w;                     w += 100096 * 4;
    int*   edata = (int*)w;                     w += (size_t)N_NODES * CAP * 4;  // 25.6 MB
    unsigned short* h1b = (unsigned short*)w;   w += (size_t)N_NODES * 128 * 2;  // 25.6 MB
    float* h2    = (float*)w;                   w += (size_t)N_NODES * 2 * 4;
    unsigned short* W1f = (unsigned short*)w;   // 16384 ushort = 32 KB (16B-aligned)

    k_pre  <<<455, 256, 0, stream>>>(W1, cnt, W1f);
    k_fused<<<3907, 256, 0, stream>>>(x, W1f, ei, cnt, edata, h1b);
    k_agg1 <<<25000, 256, 0, stream>>>(h1b, edata, cnt, b1, W2, h2);
    k_agg2 <<<391, 256, 0, stream>>>(h2, edata, cnt, b2, out);
}

// Round 12
// 183.329 us; speedup vs baseline: 1.1528x; 1.0908x over previous
//
#include <hip/hip_runtime.h>
#include <stdint.h>

#define N_NODES 100000
#define N_EDGES 600000
#define CAP 64   // per-node bucket capacity (proven R8); max in-degree ~22 here
// D_IN = D_H = 128, D_OUT = 2. All float tensors fp32; edge_index int32.
// h1 stored bf16; GEMM1 on MFMA bf16. Fixed-capacity buckets (no scan).
// R7 lesson: grid.sync() ~60us/barrier on MI355X — never fuse via cooperative launch.
// R9 lesson: parity-interleaved shfl agg loop failed on HW; only half-uniform forms.
// R10 lesson: LDS is reserved for EVERY block — mixed-block fusion needs compatible
// footprints (fixed via W1 pre-baked into B-frag order, 32 KB global).
// R11: scatter ~50us is structural (600k device atomics + partial-line writebacks).

typedef __attribute__((ext_vector_type(8))) short bf16x8;
typedef __attribute__((ext_vector_type(4))) float f32x4;

__device__ __forceinline__ float bflo(unsigned int u) { return __uint_as_float(u << 16); }
__device__ __forceinline__ float bfhi(unsigned int u) { return __uint_as_float(u & 0xffff0000u); }
__device__ __forceinline__ unsigned int f2bf(float f) {  // RNE, returns low 16
    unsigned int u = __float_as_uint(f);
    return (u + 0x7fffu + ((u >> 16) & 1u)) >> 16;
}

// Pre-pass: zero cnt (blocks [0,391)) + bake W1 into MFMA B-fragment order
// (blocks [391,455)). W1f[((t*4+k0c)*64+lane)*8+j] = bf16(W1[k][n]) with
// n = t*16+(lane&15), k = k0c*32+(lane>>4)*8+j  — exactly the bf16x8 lane frag.
__global__ void k_pre(const float* __restrict__ W1, int* __restrict__ cnt,
                      unsigned short* __restrict__ W1f) {
    int b = blockIdx.x;
    if (b < 391) {
        int gid = b * 256 + threadIdx.x;   // 391*256 = 100096 exact
        cnt[gid] = 0;
        return;
    }
    int idx = (b - 391) * 256 + threadIdx.x;  // 0..16383
    int t = idx >> 11;
    int k0c = (idx >> 9) & 3;
    int lane = (idx >> 3) & 63;
    int j = idx & 7;
    int n = t * 16 + (lane & 15);
    int k = k0c * 32 + (lane >> 4) * 8 + j;
    W1f[idx] = (unsigned short)f2bf(W1[k * 128 + n]);
}

// Fused edge bucket-scatter + GEMM1 (single launch; block-range split).
// Blocks [0,2344): scatter edata[col*CAP+pos]=row, pos via atomic cnt.
// Blocks [2344,3907): h1b = bf16(x @ W1) via MFMA, 64 rows/block, B-frags
// loaded coalesced from W1f (L1/L2-hot). LDS = 17.4 KB -> 8+ blocks/CU.
__global__ __launch_bounds__(256) void k_fused(const float* __restrict__ x,
                                               const unsigned short* __restrict__ W1f,
                                               const int* __restrict__ ei,
                                               int* __restrict__ cnt,
                                               int* __restrict__ edata,
                                               unsigned short* __restrict__ h1b) {
    __shared__ unsigned short sxb[64][136];   // x tile bf16; reused for D staging
    const int tid = threadIdx.x;
    const int b = blockIdx.x;
    if (b < 2344) {                           // ---- scatter part ----
        int e = b * 256 + tid;
        if (e < N_EDGES) {
            int r = ei[e];
            int c = ei[N_EDGES + e];
            int pos = atomicAdd(&cnt[c], 1);
            if (pos < CAP) edata[(size_t)c * CAP + pos] = r;
        }
        return;
    }
    // ---- GEMM part ----
    const int rowBase = (b - 2344) * 64;
#pragma unroll
    for (int i = 0; i < 8; i++) {            // stage x: 2048 float4 -> bf16
        int flat = tid + 256 * i;
        int row = flat >> 5;
        int f4 = flat & 31;
        int grow = rowBase + row;
        if (grow > N_NODES - 1) grow = N_NODES - 1;
        float4 v = *(const float4*)(x + (size_t)grow * 128 + f4 * 4);
        ushort4 p;
        p.x = (unsigned short)f2bf(v.x);
        p.y = (unsigned short)f2bf(v.y);
        p.z = (unsigned short)f2bf(v.z);
        p.w = (unsigned short)f2bf(v.w);
        *(ushort4*)(&sxb[row][f4 * 4]) = p;
    }
    __syncthreads();

    const int wv = tid >> 6;
    const int lane = tid & 63;
    const int l16 = lane & 15;
    const int quad = lane >> 4;
    const bf16x8* __restrict__ wf = (const bf16x8*)W1f;
    f32x4 acc[8];
#pragma unroll
    for (int t = 0; t < 8; t++) acc[t] = (f32x4){0.f, 0.f, 0.f, 0.f};

#pragma unroll
    for (int k0c = 0; k0c < 4; k0c++) {
        bf16x8 a = *(const bf16x8*)(&sxb[wv * 16 + l16][k0c * 32 + quad * 8]);
#pragma unroll
        for (int t = 0; t < 8; t++) {
            bf16x8 bfr = wf[(t * 4 + k0c) * 64 + lane];   // coalesced, L1-hot
            acc[t] = __builtin_amdgcn_mfma_f32_16x16x32_bf16(a, bfr, acc[t], 0, 0, 0);
        }
    }
    __syncthreads();                          // LDS reads done; reuse sxb for D
#pragma unroll
    for (int t = 0; t < 8; t++)
#pragma unroll
        for (int r = 0; r < 4; r++)
            sxb[wv * 16 + quad * 4 + r][t * 16 + l16] = (unsigned short)f2bf(acc[t][r]);
    __syncthreads();
#pragma unroll
    for (int i = 0; i < 4; i++) {             // coalesced store: 1024 uint4
        int flat = tid + 256 * i;
        int row = flat >> 4;
        int c8 = flat & 15;
        int grow = rowBase + row;
        if (grow < N_NODES)
            *(uint4*)(h1b + (size_t)grow * 128 + c8 * 8) = *(const uint4*)(&sxb[row][c8 * 8]);
    }
}

// Layer-1 aggregation + bias1+ReLU+GEMM2 epilogue.
// TWO nodes per wave: each 32-lane half owns one node (lane owns 4 cols via
// uint2; 32 lanes x 8B = full 256B row). Every gather instruction carries two
// independent rows -> 2x memory-level parallelism at identical bytes.
// Each half is internally uniform (own preload/cc/butterfly) — R9's parity
// interleave is NOT used. deg>32 handled by a (never-taken) uniform tail.
__global__ __launch_bounds__(256) void k_agg1(const unsigned short* __restrict__ h1b,
                                              const int* __restrict__ edata,
                                              const int* __restrict__ cnt,
                                              const float* __restrict__ b1,
                                              const float* __restrict__ W2,
                                              float* __restrict__ h2) {
    int g = blockIdx.x * 256 + threadIdx.x;
    int wave = g >> 6;          // grid: 12500 blocks * 4 waves * 2 nodes = 100000
    int lane = g & 63;
    int half = lane >> 5;
    int sub = lane & 31;
    int node = wave * 2 + half;
    int c0 = sub * 4;           // 4 bf16 cols per lane

    int c = cnt[node];          // uniform within half
    int cc = (c < CAP) ? c : CAP;
    float d = rsqrtf((float)c + 1.0f);
    float d2 = d * d;
    uint2 us = *(const uint2*)(h1b + (size_t)node * 128 + c0);
    float ax = bflo(us.x) * d2, ay = bfhi(us.x) * d2;
    float az = bflo(us.y) * d2, aw = bfhi(us.y) * d2;

    int cm = (cc < 32) ? cc : 32;
    int src_l = 0; float nrm_l = 0.0f;
    if (sub < cm) {             // preload this half's bucket entries
        src_l = edata[(size_t)node * CAP + sub];
        nrm_l = rsqrtf((float)cnt[src_l] + 1.0f) * d;
    }
    int base = half << 5;
    int i = 0;
    for (; i + 2 <= cm; i += 2) {
        int s0 = __shfl(src_l, base + i);
        int s1 = __shfl(src_l, base + i + 1);
        float n0 = __shfl(nrm_l, base + i);
        float n1 = __shfl(nrm_l, base + i + 1);
        uint2 u0 = *(const uint2*)(h1b + (size_t)s0 * 128 + c0);
        uint2 u1 = *(const uint2*)(h1b + (size_t)s1 * 128 + c0);
        ax = fmaf(bflo(u0.x), n0, ax); ay = fmaf(bfhi(u0.x), n0, ay);
        az = fmaf(bflo(u0.y), n0, az); aw = fmaf(bfhi(u0.y), n0, aw);
        ax = fmaf(bflo(u1.x), n1, ax); ay = fmaf(bfhi(u1.x), n1, ay);
        az = fmaf(bflo(u1.y), n1, az); aw = fmaf(bfhi(u1.y), n1, aw);
    }
    for (; i < cm; i++) {
        int s = __shfl(src_l, base + i);
        float n = __shfl(nrm_l, base + i);
        uint2 u = *(const uint2*)(h1b + (size_t)s * 128 + c0);
        ax = fmaf(bflo(u.x), n, ax); ay = fmaf(bfhi(u.x), n, ay);
        az = fmaf(bflo(u.y), n, az); aw = fmaf(bfhi(u.y), n, aw);
    }
    for (; i < cc; i++) {       // deg > 32: essentially never (P ~ 1e-13/node)
        int s = edata[(size_t)node * CAP + i];
        float n = rsqrtf((float)cnt[s] + 1.0f) * d;
        uint2 u = *(const uint2*)(h1b + (size_t)s * 128 + c0);
        ax = fmaf(bflo(u.x), n, ax); ay = fmaf(bfhi(u.x), n, ay);
        az = fmaf(bflo(u.y), n, az); aw = fmaf(bfhi(u.y), n, aw);
    }

    // epilogue: bias + ReLU + [1x128]@[128x2]; butterfly within the 32-half
    float4 bb = *(const float4*)(b1 + c0);
    float v0 = fmaxf(ax + bb.x, 0.0f);
    float v1 = fmaxf(ay + bb.y, 0.0f);
    float v2 = fmaxf(az + bb.z, 0.0f);
    float v3 = fmaxf(aw + bb.w, 0.0f);
    float4 wA = *(const float4*)(W2 + c0 * 2);      // W2 rows c0, c0+1
    float4 wB = *(const float4*)(W2 + c0 * 2 + 4);  // W2 rows c0+2, c0+3
    float p0 = v0 * wA.x + v1 * wA.z + v2 * wB.x + v3 * wB.z;
    float p1 = v0 * wA.y + v1 * wA.w + v2 * wB.y + v3 * wB.w;
    for (int offl = 16; offl; offl >>= 1) {
        p0 += __shfl_xor(p0, offl);
        p1 += __shfl_xor(p1, offl);
    }
    if (sub == 0) *(float2*)(h2 + (size_t)node * 2) = make_float2(p0, p1);
}

// Layer-2 aggregation: thread per node; h2 (800 KB) and cnt L2-resident.
__global__ void k_agg2(const float* __restrict__ h2, const int* __restrict__ edata,
                       const int* __restrict__ cnt, const float* __restrict__ b2,
                       float* __restrict__ out) {
    int n = blockIdx.x * 256 + threadIdx.x;
    if (n >= N_NODES) return;
    int c = cnt[n];
    int cc = (c < CAP) ? c : CAP;
    float d = rsqrtf((float)c + 1.0f);
    float d2 = d * d;
    float2 h = *(const float2*)(h2 + (size_t)n * 2);
    float o0 = h.x * d2, o1 = h.y * d2;
    for (int i = 0; i < cc; i++) {
        int src = edata[(size_t)n * CAP + i];
        float nrm = rsqrtf((float)cnt[src] + 1.0f) * d;
        float2 v = *(const float2*)(h2 + (size_t)src * 2);
        o0 = fmaf(v.x, nrm, o0);
        o1 = fmaf(v.y, nrm, o1);
    }
    *(float2*)(out + (size_t)n * 2) = make_float2(o0 + b2[0], o1 + b2[1]);
}

extern "C" void kernel_launch(void* const* d_in, const int* in_sizes, int n_in,
                              void* d_out, int out_size, void* d_ws, size_t ws_size,
                              hipStream_t stream) {
    const float* x  = (const float*)d_in[0];   // [N,128]
    const int* ei   = (const int*)d_in[1];     // [2,E] int32
    const float* W1 = (const float*)d_in[2];   // [128,128]
    const float* b1 = (const float*)d_in[3];   // [128]
    const float* W2 = (const float*)d_in[4];   // [128,2]
    const float* b2 = (const float*)d_in[5];   // [2]
    float* out = (float*)d_out;                // [N,2]

    char* w = (char*)d_ws;
    int*   cnt   = (int*)w;                     w += 100096 * 4;
    int*   edata = (int*)w;                     w += (size_t)N_NODES * CAP * 4;  // 25.6 MB
    unsigned short* h1b = (unsigned short*)w;   w += (size_t)N_NODES * 128 * 2;  // 25.6 MB
    float* h2    = (float*)w;                   w += (size_t)N_NODES * 2 * 4;
    unsigned short* W1f = (unsigned short*)w;   // 16384 ushort = 32 KB (16B-aligned)

    k_pre  <<<455, 256, 0, stream>>>(W1, cnt, W1f);
    k_fused<<<3907, 256, 0, stream>>>(x, W1f, ei, cnt, edata, h1b);
    k_agg1 <<<12500, 256, 0, stream>>>(h1b, edata, cnt, b1, W2, h2);
    k_agg2 <<<391, 256, 0, stream>>>(h2, edata, cnt, b2, out);
}